// Round 7
// baseline (2914.099 us; speedup 1.0000x reference)
//
#include <hip/hip_runtime.h>
#include <stdint.h>

// u   = 0.01 * (x @ x2h)   [B=524288, K=32, N=256]
// spk = zeros              [B, 256]
// h2h is dead (recurrent state is zero for the single time step).
//
// R4 structure (best: 205us) + three fixes:
//  1. Prefetch issued BEFORE the store burst -> in-order vmcnt retirement
//     means load waits never force store drains (R4's vmcnt(17) retired
//     16 stores every iter). Steady-state wait = vmcnt(33) (= L(i+1) +
//     S(i-1)x16 + S(i-2)x16 younger ops outstanding).
//  2. Plain stores (drop nontemporal) -> same write path as the 6.55 TB/s
//     fill kernel.
//  3. Exactly-resident grid: 1024 blocks x 4 waves = 16 waves/CU at
//     <=128 VGPR -> single launch generation, no inter-generation bubbles.

#define NHID 256
#define NINP 32
#define RPC  8            // rows per chunk: 8*128B = 1 KB = one global_load_lds_dwordx4/wave
#define BLOCKS 1024       // 4096 waves = 2048 pairs -> nch = 65536/2048 = 32 exact

typedef float __attribute__((ext_vector_type(4))) f32x4;
typedef float __attribute__((ext_vector_type(2))) f32x2;

__device__ __forceinline__ void stage_chunk(const float* src_lane, void* lds_wave_base) {
    // global src is per-lane; LDS dst is wave-uniform base + lane*16 (HW rule).
    __builtin_amdgcn_global_load_lds(
        (const __attribute__((address_space(1))) uint32_t*)src_lane,
        (__attribute__((address_space(3))) uint32_t*)lds_wave_base,
        16, 0, 0);
}

__global__ __launch_bounds__(256, 4) void lsm_kernel(
    const float* __restrict__ x, const float* __restrict__ x2h,
    float* __restrict__ u, float* __restrict__ spk,
    int B, int nwaves)
{
    __shared__ float xbuf[4][2][RPC * NINP];   // 4 waves x double-buffer x 1 KB = 8 KB

    const int lane = threadIdx.x & 63;
    const int wv   = threadIdx.x >> 6;
    const int wid  = __builtin_amdgcn_readfirstlane(blockIdx.x * 4 + wv);

    // Wave pair: even wave = cols [0,128), odd wave = cols [128,256).
    const int c = (wid & 1) * 128 + lane * 2;

    // Lane owns 2 columns; weights pre-scaled by RC*DT = 0.01. 64 VGPRs.
    f32x2 w[NINP];
#pragma unroll
    for (int k = 0; k < NINP; ++k) {
        f32x2 t = *reinterpret_cast<const f32x2*>(x2h + k * NHID + c);
        w[k] = t * 0.01f;
    }

    const int cw  = wid >> 1;                 // pair id
    const int ncw = nwaves >> 1;              // number of pairs (2048)
    const int total_chunks = B / RPC;         // 65536
    const int nch = (total_chunks - cw + ncw - 1) / ncw;   // 32 exact at default launch
    if (nch <= 0) return;

    const float* src0 = x + (size_t)cw * (RPC * NINP) + lane * 4;
    const size_t src_stride = (size_t)ncw * (RPC * NINP);  // floats per chunk step

    stage_chunk(src0, &xbuf[wv][0][0]);
    if (nch > 1) stage_chunk(src0 + src_stride, &xbuf[wv][1][0]);

    for (int i = 0; i < nch; ++i) {
        // Issue order per iter: [wait][compute][L(i+2)][S(i)x16].
        // In-order vmcnt retirement; loads are always older than same-iter
        // stores, so each wait retires exactly L(i) and NO stores:
        //   i==0:    outstanding {L0,L1}                                   -> vmcnt(1)
        //   i==1:    outstanding {L1,L2,S0x16}                             -> vmcnt(17)
        //   steady:  outstanding {L(i),S(i-2)x16,L(i+1),S(i-1)x16} = 34    -> vmcnt(33)
        //   i==n-1:  outstanding {L(n-1),S(n-3)x16,S(n-2)x16} = 33         -> vmcnt(32)
        if (i == 0)            asm volatile("s_waitcnt vmcnt(1)"  ::: "memory");
        else if (i == 1)       asm volatile("s_waitcnt vmcnt(17)" ::: "memory");
        else if (i == nch - 1) asm volatile("s_waitcnt vmcnt(32)" ::: "memory");
        else                   asm volatile("s_waitcnt vmcnt(33)" ::: "memory");

        const float* xb = &xbuf[wv][i & 1][0];
        const size_t row0 = ((size_t)cw + (size_t)i * ncw) * RPC;

        // ---- compute all 8 rows into registers (consumes buf[i&1]) ----
        f32x2 acc[RPC];
#pragma unroll
        for (int r = 0; r < RPC; ++r) {
            const f32x4* xr = (const f32x4*)(xb + r * NINP);   // uniform addr -> broadcast
            f32x2 a = {0.f, 0.f};
#pragma unroll
            for (int g = 0; g < 8; ++g) {
                f32x4 xq = xr[g];
                a += w[4 * g + 0] * xq.x;
                a += w[4 * g + 1] * xq.y;
                a += w[4 * g + 2] * xq.z;
                a += w[4 * g + 3] * xq.w;
            }
            acc[r] = a;
        }

        // ---- prefetch BEFORE the store burst (buf consumed above) ----
        if (i + 2 < nch) stage_chunk(src0 + (size_t)(i + 2) * src_stride, &xbuf[wv][i & 1][0]);

        // ---- store burst: plain (cached) stores, full 64B lines/wave ----
        const f32x2 z = {0.f, 0.f};
#pragma unroll
        for (int r = 0; r < RPC; ++r) {
            const size_t base = (row0 + r) * NHID + c;
            *(f32x2*)(u + base)   = acc[r];
            *(f32x2*)(spk + base) = z;
        }
    }
}

extern "C" void kernel_launch(void* const* d_in, const int* in_sizes, int n_in,
                              void* d_out, int out_size, void* d_ws, size_t ws_size,
                              hipStream_t stream) {
    const float* x   = (const float*)d_in[0];
    const float* x2h = (const float*)d_in[1];
    // d_in[2] (h2h) is dead: recurrent input state is zero.

    const int B = in_sizes[0] / NINP;            // 524288
    float* u   = (float*)d_out;
    float* spk = u + (size_t)B * NHID;

    const int threads = 256;                     // 4 waves/block
    const int nwaves  = BLOCKS * (threads / 64); // 4096 waves, all resident
    lsm_kernel<<<BLOCKS, threads, 0, stream>>>(x, x2h, u, spk, B, nwaves);
}

// Round 8
// 2493.946 us; speedup vs baseline: 1.1685x; 1.1685x over previous
//
#include <hip/hip_runtime.h>
#include <stdint.h>

// u   = 0.01 * (x @ x2h)   [B=524288, K=32, N=256]
// spk = zeros              [B, 256]
// h2h is dead (recurrent state is zero for the single time step).
//
// R4 structure restored (nontemporal stores are MANDATORY: R7 showed plain
// stores write-allocate and amplify HBM traffic 6-10x -> 2914us). Single
// delta vs R4: prefetch is issued BEFORE the store burst, with recounted
// vmcnt so a load-wait retires only loads, never a store burst.

#define NHID 256
#define NINP 32
#define RPC  8            // rows per chunk: 8*128B = 1 KB = one global_load_lds_dwordx4/wave
#define BLOCKS 4096       // 16384 waves = 8192 pairs -> nch = 65536/8192 = 8 exact

typedef float __attribute__((ext_vector_type(4))) f32x4;
typedef float __attribute__((ext_vector_type(2))) f32x2;

__device__ __forceinline__ void stage_chunk(const float* src_lane, void* lds_wave_base) {
    // global src is per-lane; LDS dst is wave-uniform base + lane*16 (HW rule).
    __builtin_amdgcn_global_load_lds(
        (const __attribute__((address_space(1))) uint32_t*)src_lane,
        (__attribute__((address_space(3))) uint32_t*)lds_wave_base,
        16, 0, 0);
}

__global__ __launch_bounds__(256, 4) void lsm_kernel(
    const float* __restrict__ x, const float* __restrict__ x2h,
    float* __restrict__ u, float* __restrict__ spk,
    int B, int nwaves)
{
    __shared__ float xbuf[4][2][RPC * NINP];   // 4 waves x double-buffer x 1 KB = 8 KB

    const int lane = threadIdx.x & 63;
    const int wv   = threadIdx.x >> 6;
    const int wid  = __builtin_amdgcn_readfirstlane(blockIdx.x * 4 + wv);

    // Wave pair: even wave = cols [0,128), odd wave = cols [128,256).
    const int c = (wid & 1) * 128 + lane * 2;

    // Lane owns 2 columns; weights pre-scaled by RC*DT = 0.01. 64 VGPRs.
    f32x2 w[NINP];
#pragma unroll
    for (int k = 0; k < NINP; ++k) {
        f32x2 t = *reinterpret_cast<const f32x2*>(x2h + k * NHID + c);
        w[k] = t * 0.01f;
    }

    const int cw  = wid >> 1;                 // pair id
    const int ncw = nwaves >> 1;              // number of pairs (8192)
    const int total_chunks = B / RPC;         // 65536
    const int nch = (total_chunks - cw + ncw - 1) / ncw;   // 8 exact at default launch
    if (nch <= 0) return;

    const float* src0 = x + (size_t)cw * (RPC * NINP) + lane * 4;
    const size_t src_stride = (size_t)ncw * (RPC * NINP);  // floats per chunk step

    stage_chunk(src0, &xbuf[wv][0][0]);
    if (nch > 1) stage_chunk(src0 + src_stride, &xbuf[wv][1][0]);

    for (int i = 0; i < nch; ++i) {
        // Issue order per iter: [wait][compute][L(i+2)][S(i)x16 NT].
        // In-order vmcnt retirement; loads always sit ahead of same-iter
        // stores, so each wait retires exactly L(i) and NO stores:
        //   i==0:    outstanding {L0,L1}                                 -> vmcnt(1)
        //   i==1:    outstanding {L1,L2,S0x16}                           -> vmcnt(17)
        //   steady:  outstanding {L(i),S(i-2)x16,L(i+1),S(i-1)x16} = 34  -> vmcnt(33)
        //   i==n-1:  outstanding {L(n-1),S(n-3)x16,S(n-2)x16}     = 33  -> vmcnt(32)
        if (i == 0)            asm volatile("s_waitcnt vmcnt(1)"  ::: "memory");
        else if (i == 1)       asm volatile("s_waitcnt vmcnt(17)" ::: "memory");
        else if (i == nch - 1) asm volatile("s_waitcnt vmcnt(32)" ::: "memory");
        else                   asm volatile("s_waitcnt vmcnt(33)" ::: "memory");

        const float* xb = &xbuf[wv][i & 1][0];
        const size_t row0 = ((size_t)cw + (size_t)i * ncw) * RPC;

        // ---- compute all 8 rows into registers (consumes buf[i&1]) ----
        f32x2 acc[RPC];
#pragma unroll
        for (int r = 0; r < RPC; ++r) {
            const f32x4* xr = (const f32x4*)(xb + r * NINP);   // uniform addr -> broadcast
            f32x2 a = {0.f, 0.f};
#pragma unroll
            for (int g = 0; g < 8; ++g) {
                f32x4 xq = xr[g];
                a += w[4 * g + 0] * xq.x;
                a += w[4 * g + 1] * xq.y;
                a += w[4 * g + 2] * xq.z;
                a += w[4 * g + 3] * xq.w;
            }
            acc[r] = a;
        }

        // ---- prefetch BEFORE the store burst (buf consumed above) ----
        if (i + 2 < nch) stage_chunk(src0 + (size_t)(i + 2) * src_stride, &xbuf[wv][i & 1][0]);

        // ---- store burst: nontemporal (streaming, no write-allocate) ----
        const f32x2 z = {0.f, 0.f};
#pragma unroll
        for (int r = 0; r < RPC; ++r) {
            const size_t base = (row0 + r) * NHID + c;
            __builtin_nontemporal_store(acc[r], (f32x2*)(u + base));
            __builtin_nontemporal_store(z,      (f32x2*)(spk + base));
        }
    }
}

extern "C" void kernel_launch(void* const* d_in, const int* in_sizes, int n_in,
                              void* d_out, int out_size, void* d_ws, size_t ws_size,
                              hipStream_t stream) {
    const float* x   = (const float*)d_in[0];
    const float* x2h = (const float*)d_in[1];
    // d_in[2] (h2h) is dead: recurrent input state is zero.

    const int B = in_sizes[0] / NINP;            // 524288
    float* u   = (float*)d_out;
    float* spk = u + (size_t)B * NHID;

    const int threads = 256;                     // 4 waves/block
    const int nwaves  = BLOCKS * (threads / 64); // 16384 waves
    lsm_kernel<<<BLOCKS, threads, 0, stream>>>(x, x2h, u, spk, B, nwaves);
}

// Round 9
// 204.836 us; speedup vs baseline: 14.2265x; 12.1753x over previous
//
#include <hip/hip_runtime.h>
#include <stdint.h>

// u   = 0.01 * (x @ x2h)   [B=524288, K=32, N=256]
// spk = zeros              [B, 256]
// h2h is dead (recurrent state is zero for the single time step).
//
// EXACT revert to round-4 kernel (best measured: 205.0 us, 5.55 TB/s).
// Post-R8 lesson: the R7/R8 "prefetch before store burst" restructure
// amplified HBM traffic ~10x (write-combine breakage); R4's schedule
// [wait][per-row compute+NT-store][prefetch] keeps traffic at the 1.14 GB
// ideal. Do not reorder the store burst relative to the prefetch.

#define NHID 256
#define NINP 32
#define RPC  8          // rows per chunk: 8*128B = 1 KB = one global_load_lds_dwordx4/wave

typedef float __attribute__((ext_vector_type(4))) f32x4;
typedef float __attribute__((ext_vector_type(2))) f32x2;

__device__ __forceinline__ void stage_chunk(const float* src_lane, void* lds_wave_base) {
    // global src is per-lane; LDS dst is wave-uniform base + lane*16 (HW rule).
    __builtin_amdgcn_global_load_lds(
        (const __attribute__((address_space(1))) uint32_t*)src_lane,
        (__attribute__((address_space(3))) uint32_t*)lds_wave_base,
        16, 0, 0);
}

__global__ __launch_bounds__(256, 4) void lsm_kernel(
    const float* __restrict__ x, const float* __restrict__ x2h,
    float* __restrict__ u, float* __restrict__ spk,
    int B, int nwaves)
{
    __shared__ float xbuf[4][2][RPC * NINP];   // 4 waves x double-buffer x 1 KB = 8 KB

    const int lane = threadIdx.x & 63;
    const int wv   = threadIdx.x >> 6;
    const int wid  = __builtin_amdgcn_readfirstlane(blockIdx.x * 4 + wv);

    // Wave pair: even wave = cols [0,128), odd wave = cols [128,256).
    const int half = wid & 1;
    const int c    = half * 128 + lane * 2;

    // Lane owns 2 columns; weights pre-scaled by RC*DT = 0.01. 64 VGPRs.
    f32x2 w[NINP];
#pragma unroll
    for (int k = 0; k < NINP; ++k) {
        f32x2 t = *reinterpret_cast<const f32x2*>(x2h + k * NHID + c);
        w[k] = t * 0.01f;
    }

    const int cw  = wid >> 1;                 // chunk-wave id (pair id)
    const int ncw = nwaves >> 1;              // number of pairs
    const int total_chunks = B / RPC;         // 65536
    const int nch = (total_chunks - cw + ncw - 1) / ncw;   // uniform (=8 at default launch)
    if (nch <= 0) return;

    const float* src0 = x + (size_t)cw * (RPC * NINP) + lane * 4;
    const size_t src_stride = (size_t)ncw * (RPC * NINP);  // floats per chunk step

    stage_chunk(src0, &xbuf[wv][0][0]);
    if (nch > 1) stage_chunk(src0 + src_stride, &xbuf[wv][1][0]);

    for (int i = 0; i < nch; ++i) {
        // Counted waits (L=stage load, S=store). Iter body: [wait][16xS][L(i+2)].
        //   i==0: ops newer than L0 = {L1}                   -> vmcnt(1)
        //   mid:  ops newer than Li = {S(i-1) x16, L(i+1)}   -> vmcnt(17)
        //   last: ops newer than Ln = {S(n-1) x16}           -> vmcnt(16)
        if (i == 0) {
            if (nch > 1) asm volatile("s_waitcnt vmcnt(1)" ::: "memory");
            else         asm volatile("s_waitcnt vmcnt(0)" ::: "memory");
        } else if (i == nch - 1) {
            asm volatile("s_waitcnt vmcnt(16)" ::: "memory");
        } else {
            asm volatile("s_waitcnt vmcnt(17)" ::: "memory");
        }

        const float* xb = &xbuf[wv][i & 1][0];
        const size_t row0 = ((size_t)cw + (size_t)i * ncw) * RPC;

#pragma unroll 2
        for (int r = 0; r < RPC; ++r) {
            // uniform-address LDS reads -> free 16B broadcast to all lanes
            const f32x4* xr = (const f32x4*)(xb + r * NINP);
            f32x2 acc = {0.f, 0.f};
#pragma unroll
            for (int g = 0; g < 8; ++g) {
                f32x4 xq = xr[g];
                acc += w[4 * g + 0] * xq.x;
                acc += w[4 * g + 1] * xq.y;
                acc += w[4 * g + 2] * xq.z;
                acc += w[4 * g + 3] * xq.w;
            }
            const size_t base = (row0 + r) * NHID + c;
            __builtin_nontemporal_store(acc, (f32x2*)(u + base));
            f32x2 z = {0.f, 0.f};
            __builtin_nontemporal_store(z, (f32x2*)(spk + base));
        }

        if (i + 2 < nch) stage_chunk(src0 + (size_t)(i + 2) * src_stride, &xbuf[wv][i & 1][0]);
    }
}

extern "C" void kernel_launch(void* const* d_in, const int* in_sizes, int n_in,
                              void* d_out, int out_size, void* d_ws, size_t ws_size,
                              hipStream_t stream) {
    const float* x   = (const float*)d_in[0];
    const float* x2h = (const float*)d_in[1];
    // d_in[2] (h2h) is dead: recurrent input state is zero.

    const int B = in_sizes[0] / NINP;            // 524288
    float* u   = (float*)d_out;
    float* spk = u + (size_t)B * NHID;

    const int threads = 256;                     // 4 waves/block
    const int blocks  = 4096;                    // 16384 waves = 8192 pairs -> 8 chunks/pair
    const int nwaves  = blocks * (threads / 64);
    lsm_kernel<<<blocks, threads, 0, stream>>>(x, x2h, u, spk, B, nwaves);
}